// Round 4
// baseline (147.001 us; speedup 1.0000x reference)
//
#include <hip/hip_runtime.h>
#include <stdint.h>

#define NROWS 16384
#define NC    10000
#define NF4   (NC / 4)          // 2500 float4 per row
#define BLK   512
#define KMAX  5                 // ceil(2500/512) float4 per thread
#define NWAVE (BLK / 64)
#define RPB   32                // rows per block
#define NBLK  (NROWS / RPB)     // 512 blocks = 2 per CU
#define EPSF  1e-7f

struct U2 { uint32_t a, b; };

// JAX Threefry-2x32 (20 rounds), exactly as jax/_src/prng.py. constexpr so the
// key-split results fold to compile-time constants.
__host__ __device__ constexpr U2 tf2x32(uint32_t k0, uint32_t k1,
                                        uint32_t x0, uint32_t x1) {
  const uint32_t ks2 = k0 ^ k1 ^ 0x1BD11BDAu;
  uint32_t v0 = x0 + k0, v1 = x1 + k1;
#define TF_R(r) { v0 += v1; v1 = (v1 << (r)) | (v1 >> (32 - (r))); v1 ^= v0; }
  TF_R(13) TF_R(15) TF_R(26) TF_R(6)
  v0 += k1;  v1 += ks2 + 1u;
  TF_R(17) TF_R(29) TF_R(16) TF_R(24)
  v0 += ks2; v1 += k0 + 2u;
  TF_R(13) TF_R(15) TF_R(26) TF_R(6)
  v0 += k0;  v1 += k1 + 3u;
  TF_R(17) TF_R(29) TF_R(16) TF_R(24)
  v0 += k1;  v1 += ks2 + 4u;
  TF_R(13) TF_R(15) TF_R(26) TF_R(6)
  v0 += ks2; v1 += k0 + 5u;
#undef TF_R
  return {v0, v1};
}

// key(42) -> split: computed at compile time
constexpr U2 KA = tf2x32(0u, 42u, 0u, 0u);   // k_off
constexpr U2 KB = tf2x32(0u, 42u, 0u, 1u);   // k_u

// Raw barrier: LDS-visibility only (lgkmcnt), does NOT drain vmcnt -> register
// prefetch loads stay in flight across it (m139 pattern).
__device__ __forceinline__ void bsync() {
  asm volatile("s_waitcnt lgkmcnt(0)" ::: "memory");
  __builtin_amdgcn_s_barrier();
  asm volatile("" ::: "memory");
}

__device__ __forceinline__ void load_row(float4 (&buf)[KMAX], const float4* p4) {
#pragma unroll
  for (int k = 0; k < KMAX; ++k) {
    const int idx = threadIdx.x + k * BLK;
    if (idx < NF4) buf[k] = p4[idx];
  }
}

struct Red {
  float r_ss[NWAVE], r_sp[NWAVE], r_mv[NWAVE], r_z[NWAVE];
  int   r_mi[NWAVE];
  float inv2n;
};

// Process one row held in `buf`; optionally issue prefetch of row `pfrow`
// into the SAME buf after its last read. Returns tid0's (pos - neg), 0 else.
__device__ __forceinline__ double process_row(float4 (&buf)[KMAX],
                                              const float* __restrict__ pred,
                                              const int* __restrict__ labels,
                                              float* __restrict__ out,
                                              Red& S, int row, int pfrow,
                                              bool do_pf) {
  const int tid  = threadIdx.x;
  const int lane = tid & 63;
  const int wid  = tid >> 6;

  // ---- tid0: early RNG + scalar loads (issued BEFORE prefetch -> no vmcnt drain later)
  int lab = 0, cand1 = 0;
  float p_lab = 0.f, p_c1 = 0.f, ru = 0.f;
  if (tid == 0) {
    lab = labels[row];
    const U2 h  = tf2x32(KA.a, KA.b, 0u, (uint32_t)row);
    const U2 lo = tf2x32(KA.a, KA.b, 0u, (uint32_t)(NROWS + row));
    const U2 uu = tf2x32(KB.a, KB.b, 0u, (uint32_t)row);
    const uint32_t span = 9999u, mult = 6835u;   // (2^16 % 9999)^2 % 9999
    const uint32_t off = ((h.b % span) * mult + (lo.b % span)) % span;
    ru = __uint_as_float((uu.b >> 9) | 0x3F800000u) - 1.0f;
    cand1 = (lab + 1 + (int)off) % NC;           // randint(1,C) shifted label
    const float* p = pred + (size_t)row * NC;
    p_lab = p[lab];
    p_c1  = p[cand1];
  }

  // ---- pass 1: ss, sp, max/argmax from registers ----
  float ss = 0.f, sp = 0.f, mv = -1e30f;
  int mi = 0;
#pragma unroll
  for (int k = 0; k < KMAX; ++k) {
    const int idx = tid + k * BLK;
    if (idx < NF4) {
      const float4 t = buf[k];
      ss += t.x * t.x + t.y * t.y + t.z * t.z + t.w * t.w;
      sp += t.x + t.y + t.z + t.w;
      const int b = 4 * idx;
      if (t.x > mv) { mv = t.x; mi = b;     }
      if (t.y > mv) { mv = t.y; mi = b + 1; }
      if (t.z > mv) { mv = t.z; mi = b + 2; }
      if (t.w > mv) { mv = t.w; mi = b + 3; }
    }
  }
  for (int off = 32; off > 0; off >>= 1) {
    ss += __shfl_down(ss, off, 64);
    sp += __shfl_down(sp, off, 64);
    float om = __shfl_down(mv, off, 64);
    int   oi = __shfl_down(mi, off, 64);
    if (om > mv || (om == mv && oi < mi)) { mv = om; mi = oi; }
  }
  if (lane == 0) { S.r_ss[wid] = ss; S.r_sp[wid] = sp; S.r_mv[wid] = mv; S.r_mi[wid] = mi; }
  bsync();                                   // #1
  if (tid == 0) {
    float tss = S.r_ss[0], tsp = S.r_sp[0], tmv = S.r_mv[0];
    int   tmi = S.r_mi[0];
    for (int w = 1; w < NWAVE; ++w) {
      tss += S.r_ss[w]; tsp += S.r_sp[w];
      if (S.r_mv[w] > tmv || (S.r_mv[w] == tmv && S.r_mi[w] < tmi)) {
        tmv = S.r_mv[w]; tmi = S.r_mi[w];
      }
    }
    const float norm = sqrtf(tss) + EPSF;
    out[1 + row] = norm;
    S.inv2n  = 0.5f / norm;
    S.r_sp[0] = tsp;        // stash totals for epilogue
    S.r_mv[0] = tmv;
    S.r_mi[0] = tmi;
  }
  bsync();                                   // #2
  const float inv2n = S.inv2n;

  // ---- pass 2: Z = sum exp(x) from registers ----
  float zl = 0.f;
#pragma unroll
  for (int k = 0; k < KMAX; ++k) {
    const int idx = tid + k * BLK;
    if (idx < NF4) {
      const float4 t = buf[k];
      zl += __expf(t.x * inv2n) + __expf(t.y * inv2n)
          + __expf(t.z * inv2n) + __expf(t.w * inv2n);
    }
  }
  // last read of buf done -> issue prefetch of the row after next into buf
  if (do_pf) load_row(buf, (const float4*)(pred + (size_t)pfrow * NC));

  for (int off = 32; off > 0; off >>= 1) zl += __shfl_down(zl, off, 64);
  if (lane == 0) S.r_z[wid] = zl;
  bsync();                                   // #3

  // ---- epilogue (tid0), no global loads -> prefetch stays in flight ----
  double val = 0.0;
  if (tid == 0) {
    float Z = 0.f;
    for (int w = 0; w < NWAVE; ++w) Z += S.r_z[w];
    const float sumx = S.r_sp[0] * inv2n;    // sum_j x_j
    const float pmax = S.r_mv[0];
    const int   amax = S.r_mi[0];
    const float logZ = logf(Z);
    const float eZ   = EPSF * Z;

    const float max_prob = __expf(pmax * inv2n) / Z + EPSF;
    const bool  replace  = (ru <= max_prob) && (amax != lab);
    // p[tneg] = pmax when replaced (tneg == amax), else the early-loaded p_c1
    const float p_neg = replace ? pmax : p_c1;

    // log(snorm_j + eps) ~= x_j + eZ*exp(-x_j) - logZ  (log1p linearized)
    const float x_lab = p_lab * inv2n;
    const float x_neg = p_neg * inv2n;
    const float ls_lab = x_lab + eZ * __expf(-x_lab) - logZ;
    const float ls_neg = x_neg + eZ * __expf(-x_neg) - logZ;
    const float sumlog = sumx - (float)NC * logZ;  // eZ*sum(exp(-x)) dropped (~1e2 abs vs 1.8e4 thr)

    val = (double)((sumlog - ls_lab) - ls_neg);
  }
  return val;
}

__global__ __launch_bounds__(BLK, 4)
void nnce_rows(const float* __restrict__ pred,
               const int* __restrict__ labels,
               float* __restrict__ out,       // out[0]=loss, out[1+i]=norm_i
               float* __restrict__ partial)   // per-block partial sums
{
  __shared__ Red S;
  const int r0 = blockIdx.x * RPB;

  float4 bufA[KMAX], bufB[KMAX];
  load_row(bufA, (const float4*)(pred + (size_t)r0 * NC));
  load_row(bufB, (const float4*)(pred + (size_t)(r0 + 1) * NC));

  double acc = 0.0;
#pragma unroll 1
  for (int i = 0; i < RPB; i += 2) {
    acc += process_row(bufA, pred, labels, out, S, r0 + i,     r0 + i + 2, i + 2 < RPB);
    acc += process_row(bufB, pred, labels, out, S, r0 + i + 1, r0 + i + 3, i + 3 < RPB);
  }
  if (threadIdx.x == 0) partial[blockIdx.x] = (float)acc;
}

__global__ __launch_bounds__(BLK)
void nnce_final(const float* __restrict__ partial, float* __restrict__ out) {
  __shared__ double red[BLK];
  double s = (threadIdx.x < NBLK) ? (double)partial[threadIdx.x] : 0.0;
  red[threadIdx.x] = s;
  __syncthreads();
  for (int k = BLK / 2; k > 0; k >>= 1) {
    if (threadIdx.x < k) red[threadIdx.x] += red[threadIdx.x + k];
    __syncthreads();
  }
  if (threadIdx.x == 0) out[0] = (float)(10.0 * red[0] / (double)NROWS);
}

extern "C" void kernel_launch(void* const* d_in, const int* in_sizes, int n_in,
                              void* d_out, int out_size, void* d_ws, size_t ws_size,
                              hipStream_t stream) {
  const float* pred   = (const float*)d_in[0];
  const int*   labels = (const int*)d_in[1];
  float* out     = (float*)d_out;
  float* partial = (float*)d_ws;   // 512 floats

  nnce_rows<<<NBLK, BLK, 0, stream>>>(pred, labels, out, partial);
  nnce_final<<<1, BLK, 0, stream>>>(partial, out);
}

// Round 5
// 125.887 us; speedup vs baseline: 1.1677x; 1.1677x over previous
//
#include <hip/hip_runtime.h>
#include <stdint.h>

#define NROWS 16384
#define NC    10000
#define NF4   2500              // float4 per row
#define BLK   256
#define WPB   4                 // waves per block, one row per wave
#define NBLK  (NROWS / WPB)     // 4096 blocks
#define EPSF  1e-7f

struct U2 { uint32_t a, b; };

// JAX Threefry-2x32 (20 rounds), exactly as jax/_src/prng.py.
__host__ __device__ constexpr U2 tf2x32(uint32_t k0, uint32_t k1,
                                        uint32_t x0, uint32_t x1) {
  const uint32_t ks2 = k0 ^ k1 ^ 0x1BD11BDAu;
  uint32_t v0 = x0 + k0, v1 = x1 + k1;
#define TF_R(r) { v0 += v1; v1 = (v1 << (r)) | (v1 >> (32 - (r))); v1 ^= v0; }
  TF_R(13) TF_R(15) TF_R(26) TF_R(6)
  v0 += k1;  v1 += ks2 + 1u;
  TF_R(17) TF_R(29) TF_R(16) TF_R(24)
  v0 += ks2; v1 += k0 + 2u;
  TF_R(13) TF_R(15) TF_R(26) TF_R(6)
  v0 += k0;  v1 += k1 + 3u;
  TF_R(17) TF_R(29) TF_R(16) TF_R(24)
  v0 += k1;  v1 += ks2 + 4u;
  TF_R(13) TF_R(15) TF_R(26) TF_R(6)
  v0 += ks2; v1 += k0 + 5u;
#undef TF_R
  return {v0, v1};
}

constexpr U2 KA = tf2x32(0u, 42u, 0u, 0u);   // k_off (key(42) split, compile-time)
constexpr U2 KB = tf2x32(0u, 42u, 0u, 1u);   // k_u

__global__ __launch_bounds__(BLK, 8)
void nnce_rows(const float* __restrict__ pred,
               const int* __restrict__ labels,
               float* __restrict__ out,       // out[0]=loss, out[1+i]=norm_i
               float* __restrict__ row_acc)   // per-row (pos - neg)
{
  const int tid  = threadIdx.x;
  const int lane = tid & 63;
  const int wid  = tid >> 6;
  const int row  = blockIdx.x * WPB + wid;
  const float*  p  = pred + (size_t)row * NC;
  const float4* p4 = (const float4*)p;

  // ---- early per-row scalars: label, RNG (3 hashes on 3 lanes, uniform CF) ----
  const int lab = labels[row];
  const uint32_t xin = (uint32_t)row + ((lane == 1) ? (uint32_t)NROWS : 0u);
  const uint32_t kk0 = (lane == 2) ? KB.a : KA.a;
  const uint32_t kk1 = (lane == 2) ? KB.b : KA.b;
  const U2 rr = tf2x32(kk0, kk1, 0u, xin);
  const uint32_t hb  = __shfl((int)rr.b, 0, 64);   // higher randint bits
  const uint32_t lob = __shfl((int)rr.b, 1, 64);   // lower randint bits
  const uint32_t ub  = __shfl((int)rr.b, 2, 64);   // uniform bits
  const uint32_t span = 9999u, mult = 6835u;       // (2^16 % 9999)^2 % 9999
  const uint32_t off = ((hb % span) * mult + (lob % span)) % span;
  const float ru = __uint_as_float((ub >> 9) | 0x3F800000u) - 1.0f;
  const int cand1 = (lab + 1 + (int)off) % NC;     // randint(1,C)-shifted label
  const float p_lab = p[lab];                       // issued before the stream
  const float p_c1  = p[cand1];

  // ---- single streaming pass: moments sp,ss,sc,sq + max/argmax ----
  float sp = 0.f, ss = 0.f, sc = 0.f, sq = 0.f, mv = -1e30f;
  int mi = 0;

#define PROC1(xv, e) { const float q_ = (xv) * (xv);            \
    sp += (xv); ss += q_;                                        \
    sc = fmaf(q_, (xv), sc); sq = fmaf(q_, q_, sq);              \
    if ((xv) > mv) { mv = (xv); mi = (e); } }
#define PROC4(v, e) { PROC1((v).x, (e)); PROC1((v).y, (e) + 1);  \
                      PROC1((v).z, (e) + 2); PROC1((v).w, (e) + 3); }

  int k = lane;
#pragma unroll 1
  for (int it = 0; it < 9; ++it) {            // 9 x 4 = 36 float4 per lane
    const float4 a = p4[k], b = p4[k + 64], c = p4[k + 128], d = p4[k + 192];
    PROC4(a, 4 * k);
    PROC4(b, 4 * (k + 64));
    PROC4(c, 4 * (k + 128));
    PROC4(d, 4 * (k + 192));
    k += 256;
  }
  {                                           // 3 more: k = lane + 2304
    const float4 a = p4[k], b = p4[k + 64], c = p4[k + 128];
    PROC4(a, 4 * k);
    PROC4(b, 4 * (k + 64));
    PROC4(c, 4 * (k + 128));
  }
  if (lane < 4) {                             // ragged tail: 2500 = 39*64 + 4
    const float4 t = p4[2496 + lane];
    PROC4(t, 4 * (2496 + lane));
  }
#undef PROC4
#undef PROC1

  // ---- butterfly reduce (result lands in every lane; no LDS, no barrier) ----
  for (int o = 32; o > 0; o >>= 1) {
    sp += __shfl_xor(sp, o, 64);
    ss += __shfl_xor(ss, o, 64);
    sc += __shfl_xor(sc, o, 64);
    sq += __shfl_xor(sq, o, 64);
    const float om = __shfl_xor(mv, o, 64);
    const int   oi = __shfl_xor(mi, o, 64);
    if (om > mv || (om == mv && oi < mi)) { mv = om; mi = oi; }
  }

  // ---- epilogue (uniform across the wave) ----
  const float norm  = sqrtf(ss) + EPSF;
  const float inv2n = 0.5f / norm;
  const float i2    = inv2n * inv2n;
  // Z = sum exp(x), Zm = sum exp(-x) via Taylor in moments (|x| <= ~0.03):
  const float t1 = sp * inv2n;
  const float t2 = 0.5f * ss * i2;                 // == ~0.125 by construction
  const float t3 = (1.0f / 6.0f) * sc * i2 * inv2n;
  const float t4 = (1.0f / 24.0f) * sq * i2 * i2;
  const float Z    = (float)NC + t1 + t2 + t3 + t4;
  const float Zm   = (float)NC - t1 + t2 - t3 + t4;
  const float logZ = logf(Z);
  const float eZ   = EPSF * Z;

  const float max_prob = __expf(mv * inv2n) / Z + EPSF;
  const bool  replace  = (ru <= max_prob) && (mi != lab);
  const float p_neg    = replace ? mv : p_c1;      // p[amax] == mv when replaced

  // log(snorm_j + eps) = x_j + log1p(eZ e^{-x_j}) - logZ ~= x_j + eZ(1 - x_j) - logZ
  const float x_lab  = p_lab * inv2n;
  const float x_neg  = p_neg * inv2n;
  const float ls_lab = x_lab + eZ * (1.0f - x_lab) - logZ;
  const float ls_neg = x_neg + eZ * (1.0f - x_neg) - logZ;
  const float sumlog = t1 + eZ * Zm - (float)NC * logZ;   // sum_j log(snorm_j+eps)

  if (lane == 0) {
    out[1 + row]  = norm;
    row_acc[row]  = (sumlog - ls_lab) - ls_neg;
  }
}

__global__ __launch_bounds__(1024)
void nnce_final(const float* __restrict__ row_acc, float* __restrict__ out) {
  __shared__ double red[1024];
  double s = 0.0;
  for (int i = threadIdx.x; i < NROWS; i += 1024) s += (double)row_acc[i];
  red[threadIdx.x] = s;
  __syncthreads();
  for (int k = 512; k > 0; k >>= 1) {
    if (threadIdx.x < k) red[threadIdx.x] += red[threadIdx.x + k];
    __syncthreads();
  }
  if (threadIdx.x == 0) out[0] = (float)(10.0 * red[0] / (double)NROWS);
}

extern "C" void kernel_launch(void* const* d_in, const int* in_sizes, int n_in,
                              void* d_out, int out_size, void* d_ws, size_t ws_size,
                              hipStream_t stream) {
  const float* pred   = (const float*)d_in[0];
  const int*   labels = (const int*)d_in[1];
  float* out     = (float*)d_out;
  float* row_acc = (float*)d_ws;   // 64 KB

  nnce_rows<<<NBLK, BLK, 0, stream>>>(pred, labels, out, row_acc);
  nnce_final<<<1, 1024, 0, stream>>>(row_acc, out);
}